// Round 1
// baseline (852.100 us; speedup 1.0000x reference)
//
#include <hip/hip_runtime.h>
#include <cstdint>
#include <math.h>

#define NBATCH 8
#define NANCH 262144
#define TOPK 6000
#define OUTK 1000
#define CAP 8192
#define ROWS 6016          // TOPK padded to 94*64
#define WORDS 94           // ceil(6000/64)
#define WPAD 96            // padded words per mask row
#define NMS_THR 0.7f

using u32 = uint32_t;
using u64 = unsigned long long;

// ---------------- top-k via 3-level radix histogram (12+12+8 bits) ----------------
// scores are softmax outputs in (0,1): positive floats -> bit pattern is order-monotone.

__global__ void hist_kernel(const float* __restrict__ cls, u32* __restrict__ hist,
                            const u32* __restrict__ meta, int level) {
    __shared__ u32 lh[4096];
    int b = blockIdx.y, t = threadIdx.x;
    int nbins = (level == 3) ? 256 : 4096;
    for (int i = t; i < nbins; i += 256) lh[i] = 0;
    __syncthreads();
    u32 f1 = 0, f2 = 0;
    if (level == 2) f1 = meta[b];
    if (level == 3) f2 = (meta[b] << 12) | meta[16 + b];
    for (int n = blockIdx.x * 256 + t; n < NANCH; n += gridDim.x * 256) {
        u32 key = __float_as_uint(cls[((size_t)b * NANCH + n) * 2 + 1]);
        if (level == 1) atomicAdd(&lh[key >> 20], 1);
        else if (level == 2) { if ((key >> 20) == f1) atomicAdd(&lh[(key >> 8) & 4095], 1); }
        else { if ((key >> 8) == f2) atomicAdd(&lh[key & 255], 1); }
    }
    __syncthreads();
    for (int i = t; i < nbins; i += 256) { u32 v = lh[i]; if (v) atomicAdd(&hist[b * nbins + i], v); }
}

__global__ void scan_kernel(const u32* __restrict__ hist, u32* __restrict__ meta, int level) {
    __shared__ u32 ts[256];
    int b = blockIdx.x, t = threadIdx.x;
    int nbins = (level == 3) ? 256 : 4096;
    int per = nbins / 256;
    const u32* h = hist + b * nbins;
    u32 s = 0;
    for (int k = 0; k < per; k++) s += h[t * per + k];
    ts[t] = s; __syncthreads();
    u32 suf = 0;
    for (int t2 = t + 1; t2 < 256; t2++) suf += ts[t2];
    u32 base = (level == 1) ? 0u : meta[(level == 2 ? 8 : 24) + b];
    u32 acc = base + suf;                    // count of keys strictly above my bin range
    if (acc < TOPK && acc + s >= TOPK) {     // crossing bin is inside my range
        u32 a = acc;
        for (int k = per - 1; k >= 0; k--) {
            u32 bin = (u32)(t * per + k); u32 c = h[bin];
            if (a + c >= TOPK) {
                if (level == 1)      { meta[b] = bin;      meta[8 + b] = a; }
                else if (level == 2) { meta[16 + b] = bin; meta[24 + b] = a; }
                else { meta[32 + b] = (meta[b] << 20) | (meta[16 + b] << 8) | bin; meta[40 + b] = a; }
                break;
            }
            a += c;
        }
    }
}

__global__ void compact_kernel(const float* __restrict__ cls, u32* __restrict__ meta,
                               u64* __restrict__ cand) {
    int b = blockIdx.y, t = threadIdx.x;
    u32 T = meta[32 + b];
    for (int n = blockIdx.x * 256 + t; n < NANCH; n += gridDim.x * 256) {
        u32 key = __float_as_uint(cls[((size_t)b * NANCH + n) * 2 + 1]);
        if (key >= T) {
            u32 pos = atomicAdd(&meta[48 + b], 1u);
            if (pos < CAP) cand[(size_t)b * CAP + pos] = ((u64)key << 32) | (u32)(~(u32)n);
        }
    }
}

// rank by counting (stable descending order == jax.lax.top_k), then decode+clip boxes.
__global__ void rank_kernel(const u64* __restrict__ cand, const u32* __restrict__ meta,
                            const float* __restrict__ anchors, const float* __restrict__ bbox,
                            float4* __restrict__ boxes) {
    __shared__ u64 tile[2048];
    int b = blockIdx.y, t = threadIdx.x;
    int c = blockIdx.x * 256 + t;
    u32 cnt = meta[48 + b]; if (cnt > CAP) cnt = CAP;
    const u64* cb = cand + (size_t)b * CAP;
    u64 Kc = (c < (int)cnt) ? cb[c] : 0ull;
    int rank = 0;
    for (u32 t0 = 0; t0 < cnt; t0 += 2048) {
        int m = (int)((cnt - t0 < 2048u) ? (cnt - t0) : 2048u);
        for (int q = t; q < 2048; q += 256) tile[q] = (t0 + (u32)q < cnt) ? cb[t0 + q] : 0ull;
        __syncthreads();
        #pragma unroll 8
        for (int j = 0; j < m; j++) rank += (tile[j] > Kc) ? 1 : 0;
        __syncthreads();
    }
    if (c < (int)cnt && rank < TOPK) {
        u32 idx = ~(u32)(Kc & 0xFFFFFFFFull);
        size_t off = ((size_t)b * NANCH + idx) * 4;
        const float4 a = *(const float4*)(anchors + off);
        const float4 d = *(const float4*)(bbox + off);
        // replicate reference op order exactly (fp32)
        float h = a.z - a.x, w = a.w - a.y;
        float cy = a.x + 0.5f * h, cx = a.y + 0.5f * w;
        float dy = d.x * 0.1f, dx = d.y * 0.1f, dh = d.z * 0.2f, dw = d.w * 0.2f;
        cy = cy + dy * h; cx = cx + dx * w;
        h = h * (float)exp((double)dh);
        w = w * (float)exp((double)dw);
        float y1 = cy - 0.5f * h, x1 = cx - 0.5f * w;
        float y2 = cy + 0.5f * h, x2 = cx + 0.5f * w;
        y1 = fminf(fmaxf(y1, 0.f), 1.f); x1 = fminf(fmaxf(x1, 0.f), 1.f);
        y2 = fminf(fmaxf(y2, 0.f), 1.f); x2 = fminf(fmaxf(x2, 0.f), 1.f);
        boxes[(size_t)b * ROWS + rank] = make_float4(y1, x1, y2, x2);
    }
    if (blockIdx.x == 0 && t < ROWS - TOPK)   // zero pad rows 6000..6015
        boxes[(size_t)b * ROWS + TOPK + t] = make_float4(0.f, 0.f, 0.f, 0.f);
}

// ---------------- NMS phase A: upper-triangular suppression bitmask ----------------
__global__ void nms_mask_kernel(const float4* __restrict__ boxes, u64* __restrict__ M) {
    __shared__ float4 colb[64];
    int cb = blockIdx.x;          // column tile 0..93
    int r0 = blockIdx.y * 256;    // row tile base
    int b  = blockIdx.z;
    if (cb * 64 + 63 < r0) return;   // fully below diagonal: never read by phase B
    int t = threadIdx.x;
    const float4* bx = boxes + (size_t)b * ROWS;
    if (t < 64) colb[t] = bx[cb * 64 + t];
    __syncthreads();
    int i = r0 + t;
    if (i >= TOPK) return;
    float4 bi = bx[i];
    float ai = (bi.z - bi.x) * (bi.w - bi.y);
    u64 word = 0;
    #pragma unroll 4
    for (int k = 0; k < 64; k++) {
        float4 bj = colb[k];
        float y1 = fmaxf(bi.x, bj.x), x1 = fmaxf(bi.y, bj.y);
        float y2 = fminf(bi.z, bj.z), x2 = fminf(bi.w, bj.w);
        float inter = fmaxf(y2 - y1, 0.f) * fmaxf(x2 - x1, 0.f);
        float aj = (bj.z - bj.x) * (bj.w - bj.y);
        float uni = ai + aj - inter + 1e-9f;
        float iou = inter / uni;     // IEEE div, matches reference arithmetic
        if ((cb * 64 + k) > i && iou > NMS_THR) word |= (1ull << k);
    }
    M[((size_t)b * ROWS + i) * WPAD + cb] = word;
}

// ---------------- NMS phase B: one wave per batch, removed-mask in registers ----------------
__device__ inline u64 shfl64(u64 x, int src) {
    int lo = __shfl((int)(u32)(x & 0xffffffffull), src, 64);
    int hi = __shfl((int)(u32)(x >> 32), src, 64);
    return ((u64)(u32)hi << 32) | (u32)lo;
}

__global__ __launch_bounds__(64) void nms_seq_kernel(const float4* __restrict__ boxes,
                                                     const u64* __restrict__ M,
                                                     float* __restrict__ out) {
    int b = blockIdx.x, l = threadIdx.x;
    const u64* Mb = M + (size_t)b * ROWS * WPAD;
    const float4* bx = boxes + (size_t)b * ROWS;
    float4* ob = (float4*)(out + (size_t)b * OUTK * 4);
    // lane l holds removed-mask words 2l and 2l+1 (covers 0..127 >= 94 used)
    u64 rem0 = 0, rem1 = 0;
    int kept = 0;
    const int PD = 8;   // prefetch depth: hide L3 latency of mask rows
    ulonglong2 pf[PD]; float4 pb[PD];
    #pragma unroll
    for (int k = 0; k < PD; k++) {
        pf[k] = ((const ulonglong2*)(Mb + (size_t)k * WPAD))[l];
        pb[k] = bx[k];
    }
    for (int base = 0; base < TOPK; base += PD) {
        #pragma unroll
        for (int k = 0; k < PD; k++) {
            int i = base + k;
            ulonglong2 v = pf[k]; float4 v4 = pb[k];
            int nx = i + PD; if (nx >= TOPK) nx = 0;      // speculative prefetch next row
            pf[k] = ((const ulonglong2*)(Mb + (size_t)nx * WPAD))[l];
            pb[k] = bx[nx];
            if (kept < OUTK) {
                int w = i >> 6;
                u64 rw = shfl64((w & 1) ? rem1 : rem0, w >> 1);   // uniform value
                if (!((rw >> (i & 63)) & 1ull)) {
                    if (l == 0) ob[kept] = v4;
                    rem0 |= v.x; rem1 |= v.y;   // wave-synchronous register update
                    kept++;
                }
            }
        }
        if (kept >= OUTK) break;
    }
    // tail stays zero from the d_out memset (matches valids==False -> zeros)
}

// ---------------- host ----------------
extern "C" void kernel_launch(void* const* d_in, const int* in_sizes, int n_in,
                              void* d_out, int out_size, void* d_ws, size_t ws_size,
                              hipStream_t stream) {
    const float* cls     = (const float*)d_in[0];   // rpn_class  (B,N,2)
    const float* bbox    = (const float*)d_in[1];   // rpn_bbox   (B,N,4)
    const float* anchors = (const float*)d_in[2];   // anchors    (B,N,4)

    char* ws = (char*)d_ws;
    u32* hist1 = (u32*)(ws);                        // 8*4096*4 = 131072
    u32* hist2 = (u32*)(ws + 131072);               // 131072
    u32* hist3 = (u32*)(ws + 262144);               // 8*256*4 = 8192
    u32* meta  = (u32*)(ws + 270336);               // 64 u32: sel1/cnt1/sel2/cnt2/T/cntg/candcnt
    u64* cand  = (u64*)(ws + 270592);               // 8*8192*8 = 524288
    float4* boxes = (float4*)(ws + 794880);         // 8*6016*16 = 770048
    u64* M = (u64*)(ws + 1564928);                  // 8*6016*96*8 = 36962304
    size_t need = 1564928 + (size_t)NBATCH * ROWS * WPAD * 8;

    hipMemsetAsync(d_out, 0, (size_t)out_size * 4, stream);
    if (ws_size < need) return;                     // visible failure -> restructure next round
    hipMemsetAsync(ws, 0, 270592, stream);          // hists + meta

    hist_kernel<<<dim3(64, NBATCH), 256, 0, stream>>>(cls, hist1, meta, 1);
    scan_kernel<<<NBATCH, 256, 0, stream>>>(hist1, meta, 1);
    hist_kernel<<<dim3(64, NBATCH), 256, 0, stream>>>(cls, hist2, meta, 2);
    scan_kernel<<<NBATCH, 256, 0, stream>>>(hist2, meta, 2);
    hist_kernel<<<dim3(64, NBATCH), 256, 0, stream>>>(cls, hist3, meta, 3);
    scan_kernel<<<NBATCH, 256, 0, stream>>>(hist3, meta, 3);
    compact_kernel<<<dim3(64, NBATCH), 256, 0, stream>>>(cls, meta, cand);
    rank_kernel<<<dim3(CAP / 256, NBATCH), 256, 0, stream>>>(cand, meta, anchors, bbox, boxes);
    nms_mask_kernel<<<dim3(WORDS, (TOPK + 255) / 256, NBATCH), 256, 0, stream>>>(boxes, M);
    nms_seq_kernel<<<NBATCH, 64, 0, stream>>>(boxes, M, (float*)d_out);
}

// Round 2
// 716.604 us; speedup vs baseline: 1.1891x; 1.1891x over previous
//
#include <hip/hip_runtime.h>
#include <cstdint>
#include <math.h>

#define NBATCH 8
#define NANCH 262144
#define TOPK 6000
#define OUTK 1000
#define CAP 16384
#define ROWS 6016          // TOPK padded to 94*64
#define WORDS 94           // ceil(6000/64)
#define WPAD 96            // padded words per mask row
#define NMS_THR 0.7f

using u32 = uint32_t;
using u64 = unsigned long long;

// ---------------- coarse top-k threshold: one 12-bit histogram pass ----------------
// scores are softmax outputs in (0,1): positive floats -> bit pattern order-monotone.

__global__ void hist_kernel(const float* __restrict__ cls, u32* __restrict__ hist) {
    __shared__ u32 lh[4096];
    int b = blockIdx.y, t = threadIdx.x;
    for (int i = t; i < 4096; i += 256) lh[i] = 0;
    __syncthreads();
    const float4* p4 = (const float4*)(cls + (size_t)b * NANCH * 2);
    const int P = NANCH / 2;   // float4 = 2 (bg,fg) pairs
    for (int p = blockIdx.x * 256 + t; p < P; p += gridDim.x * 256) {
        float4 v = p4[p];
        atomicAdd(&lh[__float_as_uint(v.y) >> 20], 1);
        atomicAdd(&lh[__float_as_uint(v.w) >> 20], 1);
    }
    __syncthreads();
    for (int i = t; i < 4096; i += 256) { u32 c = lh[i]; if (c) atomicAdd(&hist[b * 4096 + i], c); }
}

// find bin where descending cumulative count crosses TOPK; threshold = bin floor.
__global__ void scan_kernel(const u32* __restrict__ hist, u32* __restrict__ meta) {
    __shared__ u32 ts[256];
    int b = blockIdx.x, t = threadIdx.x;
    const u32* h = hist + b * 4096;
    u32 s = 0;
    for (int k = 0; k < 16; k++) s += h[t * 16 + k];
    ts[t] = s; __syncthreads();
    u32 suf = 0;
    for (int t2 = t + 1; t2 < 256; t2++) suf += ts[t2];
    if (suf < TOPK && suf + s >= TOPK) {
        u32 a = suf;
        for (int k = 15; k >= 0; k--) {
            u32 c = h[t * 16 + k];
            if (a + c >= TOPK) { meta[32 + b] = (u32)(t * 16 + k) << 20; break; }
            a += c;
        }
    }
}

// ---------------- compact: block-local LDS staging, ONE global atomic per block ----------------
__global__ void compact_kernel(const float* __restrict__ cls, u32* __restrict__ meta,
                               u64* __restrict__ cand) {
    __shared__ u64 buf[4096];
    __shared__ u32 lc, gbase;
    int b = blockIdx.y, t = threadIdx.x;
    if (t == 0) lc = 0;
    __syncthreads();
    u32 T = meta[32 + b];
    const float4* p4 = (const float4*)(cls + (size_t)b * NANCH * 2);
    const int P = NANCH / 2;
    for (int p = blockIdx.x * 256 + t; p < P; p += gridDim.x * 256) {
        float4 v = p4[p];
        u32 k0 = __float_as_uint(v.y), k1 = __float_as_uint(v.w);
        u32 n0 = 2u * (u32)p, n1 = n0 + 1u;
        if (k0 >= T) { u32 q = atomicAdd(&lc, 1u); buf[q] = ((u64)k0 << 32) | (u32)(~n0); }
        if (k1 >= T) { u32 q = atomicAdd(&lc, 1u); buf[q] = ((u64)k1 << 32) | (u32)(~n1); }
    }
    __syncthreads();
    if (t == 0) gbase = atomicAdd(&meta[48 + b], lc);
    __syncthreads();
    u32 base = gbase, n = lc;
    for (u32 j = t; j < n; j += 256) {
        u32 d = base + j;
        if (d < CAP) cand[(size_t)b * CAP + d] = buf[j];
    }
}

// exact stable rank by counting (== jax.lax.top_k order), then decode+clip boxes.
__global__ void rank_kernel(const u64* __restrict__ cand, const u32* __restrict__ meta,
                            const float* __restrict__ anchors, const float* __restrict__ bbox,
                            float4* __restrict__ boxes) {
    __shared__ u64 tile[2048];
    int b = blockIdx.y, t = threadIdx.x;
    int c = blockIdx.x * 256 + t;
    u32 cnt = meta[48 + b]; if (cnt > CAP) cnt = CAP;
    const u64* cb = cand + (size_t)b * CAP;
    u64 Kc = (c < (int)cnt) ? cb[c] : 0ull;
    int rank = 0;
    for (u32 t0 = 0; t0 < cnt; t0 += 2048) {
        int m = (int)((cnt - t0 < 2048u) ? (cnt - t0) : 2048u);
        for (int q = t; q < 2048; q += 256) tile[q] = (t0 + (u32)q < cnt) ? cb[t0 + q] : 0ull;
        __syncthreads();
        #pragma unroll 8
        for (int j = 0; j < m; j++) rank += (tile[j] > Kc) ? 1 : 0;
        __syncthreads();
    }
    if (c < (int)cnt && rank < TOPK) {
        u32 idx = ~(u32)(Kc & 0xFFFFFFFFull);
        size_t off = ((size_t)b * NANCH + idx) * 4;
        const float4 a = *(const float4*)(anchors + off);
        const float4 d = *(const float4*)(bbox + off);
        float h = a.z - a.x, w = a.w - a.y;
        float cy = a.x + 0.5f * h, cx = a.y + 0.5f * w;
        float dy = d.x * 0.1f, dx = d.y * 0.1f, dh = d.z * 0.2f, dw = d.w * 0.2f;
        cy = cy + dy * h; cx = cx + dx * w;
        h = h * (float)exp((double)dh);
        w = w * (float)exp((double)dw);
        float y1 = cy - 0.5f * h, x1 = cx - 0.5f * w;
        float y2 = cy + 0.5f * h, x2 = cx + 0.5f * w;
        y1 = fminf(fmaxf(y1, 0.f), 1.f); x1 = fminf(fmaxf(x1, 0.f), 1.f);
        y2 = fminf(fmaxf(y2, 0.f), 1.f); x2 = fminf(fmaxf(x2, 0.f), 1.f);
        boxes[(size_t)b * ROWS + rank] = make_float4(y1, x1, y2, x2);
    }
    if (blockIdx.x == 0 && t < ROWS - TOPK)
        boxes[(size_t)b * ROWS + TOPK + t] = make_float4(0.f, 0.f, 0.f, 0.f);
}

// ---------------- NMS phase A: upper-triangular suppression bitmask ----------------
__global__ void nms_mask_kernel(const float4* __restrict__ boxes, u64* __restrict__ M) {
    __shared__ float4 colb[64];
    int cb = blockIdx.x;          // column tile 0..93
    int r0 = blockIdx.y * 256;    // row tile base
    int b  = blockIdx.z;
    if (cb * 64 + 63 < r0) return;   // fully below diagonal: never read by phase B
    int t = threadIdx.x;
    const float4* bx = boxes + (size_t)b * ROWS;
    if (t < 64) colb[t] = bx[cb * 64 + t];
    __syncthreads();
    int i = r0 + t;
    if (i >= TOPK) return;
    float4 bi = bx[i];
    float ai = (bi.z - bi.x) * (bi.w - bi.y);
    u64 word = 0;
    #pragma unroll 4
    for (int k = 0; k < 64; k++) {
        float4 bj = colb[k];
        float y1 = fmaxf(bi.x, bj.x), x1 = fmaxf(bi.y, bj.y);
        float y2 = fminf(bi.z, bj.z), x2 = fminf(bi.w, bj.w);
        float inter = fmaxf(y2 - y1, 0.f) * fmaxf(x2 - x1, 0.f);
        float aj = (bj.z - bj.x) * (bj.w - bj.y);
        float uni = ai + aj - inter + 1e-9f;
        float iou = inter / uni;
        if ((cb * 64 + k) > i && iou > NMS_THR) word |= (1ull << k);
    }
    M[((size_t)b * ROWS + i) * WPAD + cb] = word;
}

// ---------------- NMS phase B: chunked bit-sweep, one wave per batch ----------------
__device__ inline u64 shfl64(u64 x, int src) {
    int lo = __shfl((int)(u32)(x & 0xffffffffull), src, 64);
    int hi = __shfl((int)(u32)(x >> 32), src, 64);
    return ((u64)(u32)hi << 32) | (u32)lo;
}

__global__ __launch_bounds__(64) void nms_seq_kernel(const float4* __restrict__ boxes,
                                                     const u64* __restrict__ M,
                                                     float* __restrict__ out) {
    int b = blockIdx.x, l = threadIdx.x;
    const u64* Mb = M + (size_t)b * ROWS * WPAD;
    const float4* bx = boxes + (size_t)b * ROWS;
    float4* ob = (float4*)(out + (size_t)b * OUTK * 4);
    // lane l owns removed-mask words 2l, 2l+1 (covers 0..127 >= 94 used)
    u64 rem0 = 0, rem1 = 0;
    int kept = 0;
    u64 dw_next = Mb[(size_t)l * WPAD + 0];   // diagonal word, chunk 0
    for (int c = 0; c < WORDS; c++) {
        int base = c * 64;
        u64 dw = dw_next;                     // loaded last iteration (latency hidden)
        u64 rw = shfl64((c & 1) ? rem1 : rem0, c >> 1);   // removed word for this chunk
        u64 valid = (base + 64 <= TOPK) ? ~0ull : ((1ull << (TOPK - base)) - 1);
        u64 alive = ~rw & valid;
        // intra-chunk greedy resolution: pure register/scalar loop on uniform masks
        u64 km = 0; int kt = kept;
        while (alive && kt < OUTK) {
            int j = __ffsll(alive) - 1;
            km |= 1ull << j; kt++;
            u64 dwj = shfl64(dw, j);          // row j's intra-chunk suppressions
            alive &= ~dwj & ~(1ull << j);
        }
        // emit kept rows of this chunk in parallel (lane l handles row base+l)
        if ((km >> l) & 1) {
            int pos = kept + __popcll(km & ((1ull << l) - 1));
            ob[pos] = bx[base + l];
        }
        kept = kt;
        if (kept >= OUTK) break;
        if (c + 1 < WORDS)                    // prefetch next chunk's diagonal words
            dw_next = Mb[(size_t)(base + 64 + l) * WPAD + (c + 1)];
        // fold kept rows' full masks into the distributed removed bitmask
        u64 t2 = km;
        while (t2) {
            int j = __ffsll(t2) - 1; t2 &= t2 - 1;
            ulonglong2 v = ((const ulonglong2*)(Mb + (size_t)(base + j) * WPAD))[l];
            rem0 |= v.x; rem1 |= v.y;
        }
    }
    // tail stays zero from the d_out memset (matches valids==False -> zeros)
}

// ---------------- host ----------------
extern "C" void kernel_launch(void* const* d_in, const int* in_sizes, int n_in,
                              void* d_out, int out_size, void* d_ws, size_t ws_size,
                              hipStream_t stream) {
    const float* cls     = (const float*)d_in[0];   // rpn_class  (B,N,2)
    const float* bbox    = (const float*)d_in[1];   // rpn_bbox   (B,N,4)
    const float* anchors = (const float*)d_in[2];   // anchors    (B,N,4)

    char* ws = (char*)d_ws;
    u32* hist1 = (u32*)(ws);                        // 8*4096*4 = 131072
    u32* meta  = (u32*)(ws + 131072);               // 64 u32: threshold @32+b, count @48+b
    float4* boxes = (float4*)(ws + 131328);         // 8*6016*16 = 770048 -> end 901376
    u64* M = (u64*)(ws + 901376);                   // 8*6016*96*8 = 36962304 -> end 37863680
    u64* cand = M;                                  // overlay: cand (1 MB) dead before M written
    size_t need = 901376 + (size_t)NBATCH * ROWS * WPAD * 8;

    hipMemsetAsync(d_out, 0, (size_t)out_size * 4, stream);
    if (ws_size < need) return;
    hipMemsetAsync(ws, 0, 131328, stream);          // hist + meta

    hist_kernel<<<dim3(64, NBATCH), 256, 0, stream>>>(cls, hist1);
    scan_kernel<<<NBATCH, 256, 0, stream>>>(hist1, meta);
    compact_kernel<<<dim3(64, NBATCH), 256, 0, stream>>>(cls, meta, cand);
    rank_kernel<<<dim3(CAP / 256, NBATCH), 256, 0, stream>>>(cand, meta, anchors, bbox, boxes);
    nms_mask_kernel<<<dim3(WORDS, (TOPK + 255) / 256, NBATCH), 256, 0, stream>>>(boxes, M);
    nms_seq_kernel<<<NBATCH, 64, 0, stream>>>(boxes, M, (float*)d_out);
}

// Round 3
// 473.274 us; speedup vs baseline: 1.8004x; 1.5141x over previous
//
#include <hip/hip_runtime.h>
#include <cstdint>
#include <math.h>

#define NBATCH 8
#define NANCH 262144
#define TOPK 6000
#define OUTK 1000
#define CAP 16384
#define ROWS 6016          // TOPK padded to 94*64
#define WORDS 94           // ceil(6000/64)
#define WPAD 96            // padded words per mask row
#define NMS_THR 0.7f

using u32 = uint32_t;
using u64 = unsigned long long;

// ---------------- coarse top-k threshold: one 12-bit histogram pass ----------------
// scores are softmax outputs in (0,1): positive floats -> bit pattern order-monotone.

__global__ void hist_kernel(const float* __restrict__ cls, u32* __restrict__ hist) {
    __shared__ u32 lh[4096];
    int b = blockIdx.y, t = threadIdx.x;
    for (int i = t; i < 4096; i += 256) lh[i] = 0;
    __syncthreads();
    const float4* p4 = (const float4*)(cls + (size_t)b * NANCH * 2);
    const int P = NANCH / 2;   // float4 = 2 (bg,fg) pairs
    for (int p = blockIdx.x * 256 + t; p < P; p += gridDim.x * 256) {
        float4 v = p4[p];
        atomicAdd(&lh[__float_as_uint(v.y) >> 20], 1);
        atomicAdd(&lh[__float_as_uint(v.w) >> 20], 1);
    }
    __syncthreads();
    for (int i = t; i < 4096; i += 256) { u32 c = lh[i]; if (c) atomicAdd(&hist[b * 4096 + i], c); }
}

// find bin where descending cumulative count crosses TOPK; threshold = bin floor.
__global__ void scan_kernel(const u32* __restrict__ hist, u32* __restrict__ meta) {
    __shared__ u32 ts[256];
    int b = blockIdx.x, t = threadIdx.x;
    const u32* h = hist + b * 4096;
    u32 s = 0;
    for (int k = 0; k < 16; k++) s += h[t * 16 + k];
    ts[t] = s; __syncthreads();
    u32 suf = 0;
    for (int t2 = t + 1; t2 < 256; t2++) suf += ts[t2];
    if (suf < TOPK && suf + s >= TOPK) {
        u32 a = suf;
        for (int k = 15; k >= 0; k--) {
            u32 c = h[t * 16 + k];
            if (a + c >= TOPK) { meta[32 + b] = (u32)(t * 16 + k) << 20; break; }
            a += c;
        }
    }
}

// ---------------- compact: block-local LDS staging, ONE global atomic per block ----------------
__global__ void compact_kernel(const float* __restrict__ cls, u32* __restrict__ meta,
                               u64* __restrict__ cand) {
    __shared__ u64 buf[4096];
    __shared__ u32 lc, gbase;
    int b = blockIdx.y, t = threadIdx.x;
    if (t == 0) lc = 0;
    __syncthreads();
    u32 T = meta[32 + b];
    const float4* p4 = (const float4*)(cls + (size_t)b * NANCH * 2);
    const int P = NANCH / 2;
    for (int p = blockIdx.x * 256 + t; p < P; p += gridDim.x * 256) {
        float4 v = p4[p];
        u32 k0 = __float_as_uint(v.y), k1 = __float_as_uint(v.w);
        u32 n0 = 2u * (u32)p, n1 = n0 + 1u;
        if (k0 >= T) { u32 q = atomicAdd(&lc, 1u); buf[q] = ((u64)k0 << 32) | (u32)(~n0); }
        if (k1 >= T) { u32 q = atomicAdd(&lc, 1u); buf[q] = ((u64)k1 << 32) | (u32)(~n1); }
    }
    __syncthreads();
    if (t == 0) gbase = atomicAdd(&meta[48 + b], lc);
    __syncthreads();
    u32 base = gbase, n = lc;
    for (u32 j = t; j < n; j += 256) {
        u32 d = base + j;
        if (d < CAP) cand[(size_t)b * CAP + d] = buf[j];
    }
}

// exact stable rank by counting (== jax.lax.top_k order), then decode+clip boxes.
__global__ void rank_kernel(const u64* __restrict__ cand, const u32* __restrict__ meta,
                            const float* __restrict__ anchors, const float* __restrict__ bbox,
                            float4* __restrict__ boxes) {
    __shared__ u64 tile[2048];
    int b = blockIdx.y, t = threadIdx.x;
    int c = blockIdx.x * 256 + t;
    u32 cnt = meta[48 + b]; if (cnt > CAP) cnt = CAP;
    if (blockIdx.x == 0 && t < ROWS - TOPK)   // zero pad rows 6000..6015
        boxes[(size_t)blockIdx.y * ROWS + TOPK + t] = make_float4(0.f, 0.f, 0.f, 0.f);
    if (blockIdx.x * 256 >= (int)cnt) return; // whole block past candidate count
    const u64* cb = cand + (size_t)b * CAP;
    u64 Kc = (c < (int)cnt) ? cb[c] : 0ull;
    int rank = 0;
    for (u32 t0 = 0; t0 < cnt; t0 += 2048) {
        int m = (int)((cnt - t0 < 2048u) ? (cnt - t0) : 2048u);
        for (int q = t; q < 2048; q += 256) tile[q] = (t0 + (u32)q < cnt) ? cb[t0 + q] : 0ull;
        __syncthreads();
        #pragma unroll 8
        for (int j = 0; j < m; j++) rank += (tile[j] > Kc) ? 1 : 0;
        __syncthreads();
    }
    if (c < (int)cnt && rank < TOPK) {
        u32 idx = ~(u32)(Kc & 0xFFFFFFFFull);
        size_t off = ((size_t)b * NANCH + idx) * 4;
        const float4 a = *(const float4*)(anchors + off);
        const float4 d = *(const float4*)(bbox + off);
        float h = a.z - a.x, w = a.w - a.y;
        float cy = a.x + 0.5f * h, cx = a.y + 0.5f * w;
        float dy = d.x * 0.1f, dx = d.y * 0.1f, dh = d.z * 0.2f, dw = d.w * 0.2f;
        cy = cy + dy * h; cx = cx + dx * w;
        h = h * (float)exp((double)dh);
        w = w * (float)exp((double)dw);
        float y1 = cy - 0.5f * h, x1 = cx - 0.5f * w;
        float y2 = cy + 0.5f * h, x2 = cx + 0.5f * w;
        y1 = fminf(fmaxf(y1, 0.f), 1.f); x1 = fminf(fmaxf(x1, 0.f), 1.f);
        y2 = fminf(fmaxf(y2, 0.f), 1.f); x2 = fminf(fmaxf(x2, 0.f), 1.f);
        boxes[(size_t)b * ROWS + rank] = make_float4(y1, x1, y2, x2);
    }
}

// ---------------- NMS phase A: upper-triangular suppression bitmask ----------------
__global__ void nms_mask_kernel(const float4* __restrict__ boxes, u64* __restrict__ M) {
    __shared__ float4 colb[64];
    int cb = blockIdx.x;          // column tile 0..93
    int r0 = blockIdx.y * 256;    // row tile base
    int b  = blockIdx.z;
    if (cb * 64 + 63 < r0) return;   // fully below diagonal: never read by phase B
    int t = threadIdx.x;
    const float4* bx = boxes + (size_t)b * ROWS;
    if (t < 64) colb[t] = bx[cb * 64 + t];
    __syncthreads();
    int i = r0 + t;
    if (i >= TOPK) return;
    float4 bi = bx[i];
    float ai = (bi.z - bi.x) * (bi.w - bi.y);
    u64 word = 0;
    #pragma unroll 4
    for (int k = 0; k < 64; k++) {
        float4 bj = colb[k];
        float y1 = fmaxf(bi.x, bj.x), x1 = fmaxf(bi.y, bj.y);
        float y2 = fminf(bi.z, bj.z), x2 = fminf(bi.w, bj.w);
        float inter = fmaxf(y2 - y1, 0.f) * fmaxf(x2 - x1, 0.f);
        float aj = (bj.z - bj.x) * (bj.w - bj.y);
        float uni = ai + aj - inter + 1e-9f;
        float iou = inter / uni;     // IEEE div, matches reference arithmetic
        if ((cb * 64 + k) > i && iou > NMS_THR) word |= (1ull << k);
    }
    M[((size_t)b * ROWS + i) * WPAD + cb] = word;
}

// ---------------- NMS phase B: lazy rem, lane-parallel gather, one wave per batch --------
__device__ inline u64 shfl64(u64 x, int src) {
    int lo = __shfl((int)(u32)(x & 0xffffffffull), src, 64);
    int hi = __shfl((int)(u32)(x >> 32), src, 64);
    return ((u64)(u32)hi << 32) | (u32)lo;
}
__device__ inline u64 shfl64x(u64 x, int m) {
    int lo = __shfl_xor((int)(u32)(x & 0xffffffffull), m, 64);
    int hi = __shfl_xor((int)(u32)(x >> 32), m, 64);
    return ((u64)(u32)hi << 32) | (u32)lo;
}

__global__ __launch_bounds__(64) void nms_seq_kernel(const float4* __restrict__ boxes,
                                                     const u64* __restrict__ M,
                                                     float* __restrict__ out) {
    __shared__ u32 keptIdx[1024];
    int b = blockIdx.x, l = threadIdx.x;
    const u64* Mb = M + (size_t)b * ROWS * WPAD;
    const float4* bx = boxes + (size_t)b * ROWS;
    float4* ob = (float4*)(out + (size_t)b * OUTK * 4);
    int kept = 0;
    for (int c = 0; c < WORDS; c++) {
        int base = c * 64;
        // diagonal word of row base+l (issued first; overlaps the gather latency)
        u64 dw = Mb[(size_t)(base + l) * WPAD + c];
        // lazy removed-word for this chunk: OR of word c over all kept rows so far.
        // <=16 independent gathers/lane, clamp-duplicate (OR idempotent), one round-trip.
        u64 part = 0;
        int K = kept;
        if (K > 0) {
            u32 idxs[16];
            #pragma unroll
            for (int u = 0; u < 16; u++) {
                int k = l + u * 64;
                idxs[u] = keptIdx[(k < K) ? k : K - 1];
            }
            #pragma unroll
            for (int u = 0; u < 16; u++)
                part |= Mb[(size_t)idxs[u] * WPAD + c];
        }
        #pragma unroll
        for (int s = 32; s >= 1; s >>= 1) part |= shfl64x(part, s);   // now uniform
        u64 valid = (base + 64 <= TOPK) ? ~0ull : ((1ull << (TOPK - base)) - 1);
        u64 alive = ~part & valid;
        // intra-chunk greedy resolution on uniform masks
        u64 km = 0; int kt = kept;
        while (alive && kt < OUTK) {
            int j = __ffsll(alive) - 1;
            km |= 1ull << j; kt++;
            u64 dwj = shfl64(dw, j);          // row (base+j)'s intra-chunk suppressions
            alive &= ~dwj & ~(1ull << j);
        }
        // emit kept rows of this chunk in parallel; append indices to LDS list
        if ((km >> l) & 1) {
            int pos = kept + __popcll(km & ((1ull << l) - 1));
            ob[pos] = bx[base + l];
            keptIdx[pos] = (u32)(base + l);
        }
        kept = kt;
        if (kept >= OUTK) break;
        __syncthreads();   // keptIdx visible to next chunk's gather
    }
    // tail stays zero from the d_out memset (matches valids==False -> zeros)
}

// ---------------- host ----------------
extern "C" void kernel_launch(void* const* d_in, const int* in_sizes, int n_in,
                              void* d_out, int out_size, void* d_ws, size_t ws_size,
                              hipStream_t stream) {
    const float* cls     = (const float*)d_in[0];   // rpn_class  (B,N,2)
    const float* bbox    = (const float*)d_in[1];   // rpn_bbox   (B,N,4)
    const float* anchors = (const float*)d_in[2];   // anchors    (B,N,4)

    char* ws = (char*)d_ws;
    u32* hist1 = (u32*)(ws);                        // 8*4096*4 = 131072
    u32* meta  = (u32*)(ws + 131072);               // 64 u32: threshold @32+b, count @48+b
    float4* boxes = (float4*)(ws + 131328);         // 8*6016*16 = 770048 -> end 901376
    u64* M = (u64*)(ws + 901376);                   // 8*6016*96*8 = 36962304 -> end 37863680
    u64* cand = M;                                  // overlay: cand (1 MB) dead before M written
    size_t need = 901376 + (size_t)NBATCH * ROWS * WPAD * 8;

    hipMemsetAsync(d_out, 0, (size_t)out_size * 4, stream);
    if (ws_size < need) return;
    hipMemsetAsync(ws, 0, 131328, stream);          // hist + meta

    hist_kernel<<<dim3(64, NBATCH), 256, 0, stream>>>(cls, hist1);
    scan_kernel<<<NBATCH, 256, 0, stream>>>(hist1, meta);
    compact_kernel<<<dim3(64, NBATCH), 256, 0, stream>>>(cls, meta, cand);
    rank_kernel<<<dim3(CAP / 256, NBATCH), 256, 0, stream>>>(cand, meta, anchors, bbox, boxes);
    nms_mask_kernel<<<dim3(WORDS, (TOPK + 255) / 256, NBATCH), 256, 0, stream>>>(boxes, M);
    nms_seq_kernel<<<NBATCH, 64, 0, stream>>>(boxes, M, (float*)d_out);
}

// Round 4
// 435.043 us; speedup vs baseline: 1.9587x; 1.0879x over previous
//
#include <hip/hip_runtime.h>
#include <cstdint>
#include <math.h>

#define NBATCH 8
#define NANCH 262144
#define TOPK 6000
#define OUTK 1000
#define CAP 16384
#define ROWS 6016          // TOPK padded to 94*64
#define WORDS 94           // ceil(6000/64)
#define NMS_THR 0.7f

using u32 = uint32_t;
using u64 = unsigned long long;

// ---------------- coarse top-k threshold: one 12-bit histogram pass ----------------
__global__ void hist_kernel(const float* __restrict__ cls, u32* __restrict__ hist) {
    __shared__ u32 lh[4096];
    int b = blockIdx.y, t = threadIdx.x;
    for (int i = t; i < 4096; i += 256) lh[i] = 0;
    __syncthreads();
    const float4* p4 = (const float4*)(cls + (size_t)b * NANCH * 2);
    const int P = NANCH / 2;
    for (int p = blockIdx.x * 256 + t; p < P; p += gridDim.x * 256) {
        float4 v = p4[p];
        atomicAdd(&lh[__float_as_uint(v.y) >> 20], 1);
        atomicAdd(&lh[__float_as_uint(v.w) >> 20], 1);
    }
    __syncthreads();
    for (int i = t; i < 4096; i += 256) { u32 c = lh[i]; if (c) atomicAdd(&hist[b * 4096 + i], c); }
}

__global__ void scan_kernel(const u32* __restrict__ hist, u32* __restrict__ meta) {
    __shared__ u32 ts[256];
    int b = blockIdx.x, t = threadIdx.x;
    const u32* h = hist + b * 4096;
    u32 s = 0;
    for (int k = 0; k < 16; k++) s += h[t * 16 + k];
    ts[t] = s; __syncthreads();
    u32 suf = 0;
    for (int t2 = t + 1; t2 < 256; t2++) suf += ts[t2];
    if (suf < TOPK && suf + s >= TOPK) {
        u32 a = suf;
        for (int k = 15; k >= 0; k--) {
            u32 c = h[t * 16 + k];
            if (a + c >= TOPK) { meta[32 + b] = (u32)(t * 16 + k) << 20; break; }
            a += c;
        }
    }
}

// ---------------- compact: LDS staging, one global atomic per block ----------------
__global__ void compact_kernel(const float* __restrict__ cls, u32* __restrict__ meta,
                               u64* __restrict__ cand) {
    __shared__ u64 buf[4096];
    __shared__ u32 lc, gbase;
    int b = blockIdx.y, t = threadIdx.x;
    if (t == 0) lc = 0;
    __syncthreads();
    u32 T = meta[32 + b];
    const float4* p4 = (const float4*)(cls + (size_t)b * NANCH * 2);
    const int P = NANCH / 2;
    for (int p = blockIdx.x * 256 + t; p < P; p += gridDim.x * 256) {
        float4 v = p4[p];
        u32 k0 = __float_as_uint(v.y), k1 = __float_as_uint(v.w);
        u32 n0 = 2u * (u32)p, n1 = n0 + 1u;
        if (k0 >= T) { u32 q = atomicAdd(&lc, 1u); buf[q] = ((u64)k0 << 32) | (u32)(~n0); }
        if (k1 >= T) { u32 q = atomicAdd(&lc, 1u); buf[q] = ((u64)k1 << 32) | (u32)(~n1); }
    }
    __syncthreads();
    if (t == 0) gbase = atomicAdd(&meta[48 + b], lc);
    __syncthreads();
    u32 base = gbase, n = lc;
    for (u32 j = t; j < n; j += 256) {
        u32 d = base + j;
        if (d < CAP) cand[(size_t)b * CAP + d] = buf[j];
    }
}

// ---------------- exact stable rank via 64-lane ring rotation ----------------
__device__ inline u64 shfl64(u64 x, int src) {
    int lo = __shfl((int)(u32)(x & 0xffffffffull), src, 64);
    int hi = __shfl((int)(u32)(x >> 32), src, 64);
    return ((u64)(u32)hi << 32) | (u32)lo;
}
__device__ inline u64 shfl64x(u64 x, int m) {
    int lo = __shfl_xor((int)(u32)(x & 0xffffffffull), m, 64);
    int hi = __shfl_xor((int)(u32)(x >> 32), m, 64);
    return ((u64)(u32)hi << 32) | (u32)lo;
}

__global__ void rank_kernel(const u64* __restrict__ cand, const u32* __restrict__ meta,
                            const float* __restrict__ anchors, const float* __restrict__ bbox,
                            float4* __restrict__ boxes) {
    __shared__ u64 tile[2048];
    int b = blockIdx.y, t = threadIdx.x, l = t & 63;
    int c0 = blockIdx.x * 256 + t;
    u32 cnt = meta[48 + b]; if (cnt > CAP) cnt = CAP;
    if (blockIdx.x == 0 && t < ROWS - TOPK)   // zero-pad rows 6000..6015
        boxes[(size_t)b * ROWS + TOPK + t] = make_float4(0.f, 0.f, 0.f, 0.f);
    if (blockIdx.x * 256 >= (int)cnt) return;       // uniform per block
    const u64* cb = cand + (size_t)b * CAP;
    u64 Kc = (c0 < (int)cnt) ? cb[c0] : 0ull;
    u32 rank = 0;
    for (u32 t0 = 0; t0 < cnt; t0 += 2048) {
        for (int q = t; q < 2048; q += 256)
            tile[q] = (t0 + (u32)q < cnt) ? cb[t0 + q] : 0ull;
        __syncthreads();
        u64 r[32];
        #pragma unroll
        for (int u = 0; u < 32; u++) r[u] = tile[l + (u << 6)];
        // rotate (key,count) around the wave; each stop compares vs 32 resident keys
        u64 kk = Kc; u32 cc = 0;
        for (int s = 0; s < 64; s++) {
            #pragma unroll
            for (int u = 0; u < 32; u++) cc += (r[u] > kk) ? 1u : 0u;
            int src = (l + 1) & 63;
            kk = shfl64(kk, src);
            cc = (u32)__shfl((int)cc, src, 64);
        }
        rank += cc;          // pair is home after 64 rotations
        __syncthreads();
    }
    if (c0 < (int)cnt && rank < TOPK) {
        u32 idx = ~(u32)(Kc & 0xFFFFFFFFull);
        size_t off = ((size_t)b * NANCH + idx) * 4;
        const float4 a = *(const float4*)(anchors + off);
        const float4 d = *(const float4*)(bbox + off);
        float h = a.z - a.x, w = a.w - a.y;
        float cy = a.x + 0.5f * h, cx = a.y + 0.5f * w;
        float dy = d.x * 0.1f, dx = d.y * 0.1f, dh = d.z * 0.2f, dw = d.w * 0.2f;
        cy = cy + dy * h; cx = cx + dx * w;
        h = h * (float)exp((double)dh);
        w = w * (float)exp((double)dw);
        float y1 = cy - 0.5f * h, x1 = cx - 0.5f * w;
        float y2 = cy + 0.5f * h, x2 = cx + 0.5f * w;
        y1 = fminf(fmaxf(y1, 0.f), 1.f); x1 = fminf(fmaxf(x1, 0.f), 1.f);
        y2 = fminf(fmaxf(y2, 0.f), 1.f); x2 = fminf(fmaxf(x2, 0.f), 1.f);
        boxes[(size_t)b * ROWS + rank] = make_float4(y1, x1, y2, x2);
    }
}

// ---------------- NMS phase A: column-major mask, registers + readlane, no div ----------------
// Exactness: RN(inter/uni) > 0.7f  <=>  (double)inter >= MID*(double)uni,
// MID = 0.7f + 2^-25 (midpoint to nextup; tie rounds to even = 0x3F333334 > 0.7f, hence >=).
// MID(26b) * uni(24b) = exact in f64; inter exact in f64 => decision bit-identical to f32 div.
template<bool DIAG>
__device__ inline u64 mask_tile(float4 bi, float ai, float4 cbox, float carea, int i, int cbase) {
    const double MID = (double)0.7f + 2.9802322387695312e-08;
    u64 word = 0;
    #pragma unroll
    for (int k = 0; k < 64; k++) {
        float jy1 = __int_as_float(__builtin_amdgcn_readlane(__float_as_int(cbox.x), k));
        float jx1 = __int_as_float(__builtin_amdgcn_readlane(__float_as_int(cbox.y), k));
        float jy2 = __int_as_float(__builtin_amdgcn_readlane(__float_as_int(cbox.z), k));
        float jx2 = __int_as_float(__builtin_amdgcn_readlane(__float_as_int(cbox.w), k));
        float aj  = __int_as_float(__builtin_amdgcn_readlane(__float_as_int(carea), k));
        float y1 = fmaxf(bi.x, jy1), x1 = fmaxf(bi.y, jx1);
        float y2 = fminf(bi.z, jy2), x2 = fminf(bi.w, jx2);
        float inter = fmaxf(y2 - y1, 0.f) * fmaxf(x2 - x1, 0.f);
        float uni = ai + aj - inter + 1e-9f;     // same assoc as reference
        bool sup = ((double)inter >= MID * (double)uni);
        if (DIAG) sup = sup && ((cbase + k) > i);
        word |= sup ? (1ull << k) : 0ull;
    }
    return word;
}

__global__ __launch_bounds__(64) void nms_mask_kernel(const float4* __restrict__ boxes,
                                                      u64* __restrict__ Mt) {
    int cb = blockIdx.x, rt = blockIdx.y, b = blockIdx.z;
    if (cb < rt) return;                 // below-diagonal words never read by phase B
    int l = threadIdx.x;
    const float4* bx = boxes + (size_t)b * ROWS;
    float4 cbox = bx[cb * 64 + l];       // lane l holds col box cb*64+l
    float carea = (cbox.z - cbox.x) * (cbox.w - cbox.y);
    int i = rt * 64 + l;
    float4 bi = bx[i];
    float ai = (bi.z - bi.x) * (bi.w - bi.y);
    u64 word = (cb > rt) ? mask_tile<false>(bi, ai, cbox, carea, i, cb * 64)
                         : mask_tile<true >(bi, ai, cbox, carea, i, cb * 64);
    Mt[((size_t)b * WORDS + cb) * ROWS + i] = word;   // full-cacheline coalesced store
}

// ---------------- NMS phase B: pipelined chunk sweep, memory off critical path ----------------
__global__ __launch_bounds__(64) void nms_seq_kernel(const float4* __restrict__ boxes,
                                                     const u64* __restrict__ Mt,
                                                     float* __restrict__ out) {
    __shared__ u32 keptIdx[1024];
    int b = blockIdx.x, l = threadIdx.x;
    const u64* Mb = Mt + (size_t)b * WORDS * ROWS;   // Mb[c*ROWS + row]
    const float4* bx = boxes + (size_t)b * ROWS;
    float4* ob = (float4*)(out + (size_t)b * OUTK * 4);
    int kept = 0;
    u64 rw = 0;                       // removed word for current chunk (uniform)
    u64 dw = Mb[l];                   // diag word, chunk 0
    float4 vb = bx[l];
    u64 X = Mb[(size_t)ROWS + l];     // cross word: chunk-0 rows -> word 1
    u64 gpart = 0;                    // lazy gather partial (kept chunks <= c-1 -> word c+1)
    for (int c = 0; c < WORDS; c++) {
        int base = c * 64;
        u64 valid = (base + 64 <= TOPK) ? ~0ull : ((1ull << (TOPK - base)) - 1);
        u64 alive = ~rw & valid;
        u64 km = 0; int kt = kept;
        while (alive && kt < OUTK) {             // greedy within chunk (ascending index)
            int j = __ffsll(alive) - 1;
            km |= 1ull << j; kt++;
            u64 dwj = shfl64(dw, j);
            alive &= ~dwj & ~(1ull << j);
        }
        if ((km >> l) & 1) {
            int pos = kept + __popcll(km & ((1ull << l) - 1));
            ob[pos] = vb;
            keptIdx[pos] = (u32)(base + l);
        }
        kept = kt;
        if (kept >= OUTK || c + 1 >= WORDS) break;
        // removed word for chunk c+1 = gather(kept chunks<=c-1) | masked X (chunk c kept)
        u64 acc = (((km >> l) & 1) ? X : 0ull) | gpart;
        #pragma unroll
        for (int s = 1; s < 64; s <<= 1) acc |= shfl64x(acc, s);
        rw = acc;
        int nb = base + 64;
        dw = Mb[(size_t)(c + 1) * ROWS + nb + l];   // prefetch next diag
        vb = bx[nb + l];
        gpart = 0;
        if (c + 2 < WORDS) {
            X = Mb[(size_t)(c + 2) * ROWS + nb + l];  // next cross word (contiguous)
            int K = kept;
            if (K > 0) {
                #pragma unroll
                for (int u = 0; u < 16; u++) {        // 16 independent loads/lane, OR-idempotent clamp
                    int k = l + (u << 6);
                    u32 idx = keptIdx[(k < K) ? k : K - 1];
                    gpart |= Mb[(size_t)(c + 2) * ROWS + idx];
                }
            }
        }
    }
    // tail stays zero from the d_out memset (matches valids==False -> zeros)
}

// ---------------- host ----------------
extern "C" void kernel_launch(void* const* d_in, const int* in_sizes, int n_in,
                              void* d_out, int out_size, void* d_ws, size_t ws_size,
                              hipStream_t stream) {
    const float* cls     = (const float*)d_in[0];   // rpn_class  (B,N,2)
    const float* bbox    = (const float*)d_in[1];   // rpn_bbox   (B,N,4)
    const float* anchors = (const float*)d_in[2];   // anchors    (B,N,4)

    char* ws = (char*)d_ws;
    u32* hist1 = (u32*)(ws);                        // 131072
    u32* meta  = (u32*)(ws + 131072);               // 256 B
    float4* boxes = (float4*)(ws + 131328);         // 770048 -> end 901376
    u64* Mt = (u64*)(ws + 901376);                  // 8*94*6016*8 = 36190208 -> end 37091584
    u64* cand = Mt;                                 // overlay: cand dead before Mt written
    size_t need = 901376 + (size_t)NBATCH * WORDS * ROWS * 8;

    hipMemsetAsync(d_out, 0, (size_t)out_size * 4, stream);
    if (ws_size < need) return;
    hipMemsetAsync(ws, 0, 131328, stream);          // hist + meta

    hist_kernel<<<dim3(64, NBATCH), 256, 0, stream>>>(cls, hist1);
    scan_kernel<<<NBATCH, 256, 0, stream>>>(hist1, meta);
    compact_kernel<<<dim3(64, NBATCH), 256, 0, stream>>>(cls, meta, cand);
    rank_kernel<<<dim3(CAP / 256, NBATCH), 256, 0, stream>>>(cand, meta, anchors, bbox, boxes);
    nms_mask_kernel<<<dim3(WORDS, WORDS, NBATCH), 64, 0, stream>>>(boxes, Mt);
    nms_seq_kernel<<<NBATCH, 64, 0, stream>>>(boxes, Mt, (float*)d_out);
}

// Round 6
// 399.673 us; speedup vs baseline: 2.1320x; 1.0885x over previous
//
#include <hip/hip_runtime.h>
#include <cstdint>
#include <math.h>

#define NBATCH 8
#define NANCH 262144
#define TOPK 6000
#define OUTK 1000
#define CAP 16384
#define ROWS 6016          // TOPK padded to 94*64
#define WORDS 94           // ceil(6000/64)

using u32 = uint32_t;
using u64 = unsigned long long;

// ---------------- coarse top-k threshold: one 12-bit histogram pass ----------------
__global__ void hist_kernel(const float* __restrict__ cls, u32* __restrict__ hist) {
    __shared__ u32 lh[4096];
    int b = blockIdx.y, t = threadIdx.x;
    for (int i = t; i < 4096; i += 256) lh[i] = 0;
    __syncthreads();
    const float4* p4 = (const float4*)(cls + (size_t)b * NANCH * 2);
    const int P = NANCH / 2;
    for (int p = blockIdx.x * 256 + t; p < P; p += gridDim.x * 256) {
        float4 v = p4[p];
        atomicAdd(&lh[__float_as_uint(v.y) >> 20], 1);
        atomicAdd(&lh[__float_as_uint(v.w) >> 20], 1);
    }
    __syncthreads();
    for (int i = t; i < 4096; i += 256) { u32 c = lh[i]; if (c) atomicAdd(&hist[b * 4096 + i], c); }
}

__global__ void scan_kernel(const u32* __restrict__ hist, u32* __restrict__ meta) {
    __shared__ u32 ts[256];
    int b = blockIdx.x, t = threadIdx.x;
    const u32* h = hist + b * 4096;
    u32 s = 0;
    for (int k = 0; k < 16; k++) s += h[t * 16 + k];
    ts[t] = s; __syncthreads();
    u32 suf = 0;
    for (int t2 = t + 1; t2 < 256; t2++) suf += ts[t2];
    if (suf < TOPK && suf + s >= TOPK) {
        u32 a = suf;
        for (int k = 15; k >= 0; k--) {
            u32 c = h[t * 16 + k];
            if (a + c >= TOPK) { meta[32 + b] = (u32)(t * 16 + k) << 20; break; }
            a += c;
        }
    }
}

// ---------------- compact: LDS staging, one global atomic per block ----------------
__global__ void compact_kernel(const float* __restrict__ cls, u32* __restrict__ meta,
                               u64* __restrict__ cand) {
    __shared__ u64 buf[4096];
    __shared__ u32 lc, gbase;
    int b = blockIdx.y, t = threadIdx.x;
    if (t == 0) lc = 0;
    __syncthreads();
    u32 T = meta[32 + b];
    const float4* p4 = (const float4*)(cls + (size_t)b * NANCH * 2);
    const int P = NANCH / 2;
    for (int p = blockIdx.x * 256 + t; p < P; p += gridDim.x * 256) {
        float4 v = p4[p];
        u32 k0 = __float_as_uint(v.y), k1 = __float_as_uint(v.w);
        u32 n0 = 2u * (u32)p, n1 = n0 + 1u;
        if (k0 >= T) { u32 q = atomicAdd(&lc, 1u); buf[q] = ((u64)k0 << 32) | (u32)(~n0); }
        if (k1 >= T) { u32 q = atomicAdd(&lc, 1u); buf[q] = ((u64)k1 << 32) | (u32)(~n1); }
    }
    __syncthreads();
    if (t == 0) gbase = atomicAdd(&meta[48 + b], lc);
    __syncthreads();
    u32 base = gbase, n = lc;
    for (u32 j = t; j < n; j += 256) {
        u32 d = base + j;
        if (d < CAP) cand[(size_t)b * CAP + d] = buf[j];
    }
}

// ---------------- cross-lane helpers ----------------
__device__ inline u64 shfl64(u64 x, int src) {
    int lo = __shfl((int)(u32)(x & 0xffffffffull), src, 64);
    int hi = __shfl((int)(u32)(x >> 32), src, 64);
    return ((u64)(u32)hi << 32) | (u32)lo;
}
__device__ inline u64 readlane64(u64 x, int sl) {
    u32 lo = (u32)__builtin_amdgcn_readlane((int)(u32)x, sl);
    u32 hi = (u32)__builtin_amdgcn_readlane((int)(u32)(x >> 32), sl);
    return ((u64)hi << 32) | lo;
}
// OR-reduce across 64 lanes: 5-step xor-butterfly swizzle (per 32-half) + half merge.
__device__ inline u64 wave_or64(u64 x) {
    u32 lo = (u32)x, hi = (u32)(x >> 32);
    lo |= __builtin_amdgcn_ds_swizzle(lo, 0x041F); hi |= __builtin_amdgcn_ds_swizzle(hi, 0x041F);
    lo |= __builtin_amdgcn_ds_swizzle(lo, 0x081F); hi |= __builtin_amdgcn_ds_swizzle(hi, 0x081F);
    lo |= __builtin_amdgcn_ds_swizzle(lo, 0x101F); hi |= __builtin_amdgcn_ds_swizzle(hi, 0x101F);
    lo |= __builtin_amdgcn_ds_swizzle(lo, 0x201F); hi |= __builtin_amdgcn_ds_swizzle(hi, 0x201F);
    lo |= __builtin_amdgcn_ds_swizzle(lo, 0x401F); hi |= __builtin_amdgcn_ds_swizzle(hi, 0x401F);
    u32 l0 = (u32)__builtin_amdgcn_readlane((int)lo, 0)  | (u32)__builtin_amdgcn_readlane((int)lo, 32);
    u32 h0 = (u32)__builtin_amdgcn_readlane((int)hi, 0)  | (u32)__builtin_amdgcn_readlane((int)hi, 32);
    return ((u64)h0 << 32) | l0;
}

// ---------------- exact stable rank via 64-lane ring rotation; writes boxes+areas -------
__global__ void rank_kernel(const u64* __restrict__ cand, const u32* __restrict__ meta,
                            const float* __restrict__ anchors, const float* __restrict__ bbox,
                            float4* __restrict__ boxes, float* __restrict__ areas) {
    __shared__ u64 tile[2048];
    int b = blockIdx.y, t = threadIdx.x, l = t & 63;
    int c0 = blockIdx.x * 256 + t;
    u32 cnt = meta[48 + b]; if (cnt > CAP) cnt = CAP;
    if (blockIdx.x == 0 && t < ROWS - TOPK) {   // zero-pad rows 6000..6015
        boxes[(size_t)b * ROWS + TOPK + t] = make_float4(0.f, 0.f, 0.f, 0.f);
        areas[(size_t)b * ROWS + TOPK + t] = 0.f;
    }
    if (blockIdx.x * 256 >= (int)cnt) return;
    const u64* cb = cand + (size_t)b * CAP;
    u64 Kc = (c0 < (int)cnt) ? cb[c0] : 0ull;
    u32 rank = 0;
    for (u32 t0 = 0; t0 < cnt; t0 += 2048) {
        for (int q = t; q < 2048; q += 256)
            tile[q] = (t0 + (u32)q < cnt) ? cb[t0 + q] : 0ull;
        __syncthreads();
        u64 r[32];
        #pragma unroll
        for (int u = 0; u < 32; u++) r[u] = tile[l + (u << 6)];
        u64 kk = Kc; u32 cc = 0;
        for (int s = 0; s < 64; s++) {
            #pragma unroll
            for (int u = 0; u < 32; u++) cc += (r[u] > kk) ? 1u : 0u;
            int src = (l + 1) & 63;
            kk = shfl64(kk, src);
            cc = (u32)__shfl((int)cc, src, 64);
        }
        rank += cc;
        __syncthreads();
    }
    if (c0 < (int)cnt && rank < TOPK) {
        u32 idx = ~(u32)(Kc & 0xFFFFFFFFull);
        size_t off = ((size_t)b * NANCH + idx) * 4;
        const float4 a = *(const float4*)(anchors + off);
        const float4 d = *(const float4*)(bbox + off);
        float h = a.z - a.x, w = a.w - a.y;
        float cy = a.x + 0.5f * h, cx = a.y + 0.5f * w;
        float dy = d.x * 0.1f, dx = d.y * 0.1f, dh = d.z * 0.2f, dw = d.w * 0.2f;
        cy = cy + dy * h; cx = cx + dx * w;
        h = h * (float)exp((double)dh);
        w = w * (float)exp((double)dw);
        float y1 = cy - 0.5f * h, x1 = cx - 0.5f * w;
        float y2 = cy + 0.5f * h, x2 = cx + 0.5f * w;
        y1 = fminf(fmaxf(y1, 0.f), 1.f); x1 = fminf(fmaxf(x1, 0.f), 1.f);
        y2 = fminf(fmaxf(y2, 0.f), 1.f); x2 = fminf(fmaxf(x2, 0.f), 1.f);
        boxes[(size_t)b * ROWS + rank] = make_float4(y1, x1, y2, x2);
        areas[(size_t)b * ROWS + rank] = (y2 - y1) * (x2 - x1);  // same rounding as reference
    }
}

// ---------------- NMS phase A: ballot layout (lanes=cols, rows scalar) ----------------
// Exact decision: RN(inter/uni) > 0.7f  <=>  inter >= MID*uni (reals), MID = 0.7f + 2^-25
// (tie rounds to even mantissa 0x333334 > 0.7f => >=). f32 fast path: d = fmaf(uni,-0.7f,inter);
// |d| >= 2^-18*uni => sign(d) decides (error terms ~2^-24|d| + 2^-25*uni << margin);
// else rare exact f64 fma re-test (sign of single-rounded fma == sign of exact value).
__global__ __launch_bounds__(256) void nms_mask_kernel(const float4* __restrict__ boxes,
                                                       const float* __restrict__ areas,
                                                       u64* __restrict__ Mt) {
    const double MIDD = (double)0.7f + 2.9802322387695312e-08;
    int cb = blockIdx.x, b = blockIdx.z;
    int wave = threadIdx.x >> 6, l = threadIdx.x & 63;
    int rt = blockIdx.y * 4 + wave;
    if (rt >= WORDS || cb < rt) return;          // below-diagonal tiles never read
    const float4* bx = boxes + (size_t)b * ROWS;
    const float*  ar = areas + (size_t)b * ROWS;
    float4 c4 = bx[cb * 64 + l];                 // lane l = column cb*64+l (vector load)
    float  ca = ar[cb * 64 + l];
    const float4* rb = bx + rt * 64;             // row boxes: uniform-indexed -> scalar loads
    const float*  ra = ar + rt * 64;
    u32 wlo = 0, whi = 0;                        // output words, lane=row (predicated capture)
    float4 nrb = rb[0]; float nra = ra[0];       // 1-ahead scalar prefetch
    for (int r = 0; r < 64; r++) {
        float4 r4 = nrb; float rar = nra;
        if (r < 63) { nrb = rb[r + 1]; nra = ra[r + 1]; }
        float y1 = fmaxf(r4.x, c4.x), x1 = fmaxf(r4.y, c4.y);
        float y2 = fminf(r4.z, c4.z), x2 = fminf(r4.w, c4.w);
        float inter = fmaxf(y2 - y1, 0.f) * fmaxf(x2 - x1, 0.f);
        float uni = ((rar + ca) - inter) + 1e-9f;        // assoc matches reference
        float d = fmaf(uni, -0.7f, inter);
        bool bord = fabsf(d) < uni * 3.8146973e-06f;     // 2^-18 margin
        u64 w;
        if (__any(bord)) {                                // wave-uniform branch, rare
            double td = fma((double)uni, -MIDD, (double)inter);
            w = __ballot(td >= 0.0);
        } else {
            w = __ballot(d > 0.f);
        }
        if (cb == rt) w &= (r < 63) ? (~0ull << (r + 1)) : 0ull;   // cols > row only
        // lane r captures the (wave-uniform) word for row r: v_cmp + cndmask, no writelane
        if (l == r) { wlo = (u32)(w & 0xffffffffull); whi = (u32)(w >> 32); }
    }
    u64 ww = ((u64)whi << 32) | wlo;
    Mt[((size_t)b * WORDS + cb) * ROWS + rt * 64 + l] = ww;   // coalesced full-line store
}

// ---------------- NMS phase B: scalar-unit greedy, swizzle reduce, 2-deep prefetch -------
__global__ __launch_bounds__(64) void nms_seq_kernel(const float4* __restrict__ boxes,
                                                     const u64* __restrict__ Mt,
                                                     float* __restrict__ out) {
    __shared__ u32 keptIdx[1024];
    int b = blockIdx.x, l = threadIdx.x;
    const u64* Mb = Mt + (size_t)b * WORDS * ROWS;    // Mb[word*ROWS + row]
    const float4* bx = boxes + (size_t)b * ROWS;
    float4* ob = (float4*)(out + (size_t)b * OUTK * 4);
    int kept = 0;
    u64 rw = 0;                                       // removed-word for current chunk
    // 2-deep prefetch: chunk 0 and 1 state
    u64 dw0 = Mb[l];                                  // diag word of chunk 0
    float4 vb0 = bx[l];
    u64 X0 = Mb[(size_t)ROWS + l];                    // chunk-0 rows -> word 1
    u64 dw1 = Mb[(size_t)ROWS + 64 + l];              // diag word of chunk 1
    float4 vb1 = bx[64 + l];
    u64 X1 = Mb[(size_t)2 * ROWS + 64 + l];           // chunk-1 rows -> word 2
    u64 gp = 0;                                       // gather partial for next rw (word c+1)
    for (int c = 0; c < WORDS; c++) {
        int base = c * 64;
        u64 valid = (base + 64 <= TOPK) ? ~0ull : ((1ull << (TOPK - base)) - 1);
        u64 alive = ~rw & valid;                      // wave-uniform
        u64 km = 0, xk = 0; int kt = kept;
        while (alive && kt < OUTK) {                  // greedy: SALU/readlane only
            int j = __builtin_amdgcn_readfirstlane((int)__builtin_ctzll(alive));
            km |= 1ull << j; kt++;
            u64 dwj = readlane64(dw0, j);             // row j's intra-chunk suppressions
            xk |= readlane64(X0, j);                  // row j's next-word suppressions
            alive &= ~dwj & ~(1ull << j);
        }
        if ((km >> l) & 1) {
            int pos = kept + __popcll(km & ((1ull << l) - 1));
            ob[pos] = vb0;
            keptIdx[pos] = (u32)(base + l);
        }
        kept = kt;
        if (kept >= OUTK || c + 1 >= WORDS) break;
        // rem word for chunk c+1: chunk-c kept (xk) | gathered kept chunks <= c-1 (gp)
        rw = xk | wave_or64(gp);
        __syncthreads();                              // keptIdx visible for gather
        // issue loads for chunk c+2 (consumed after one full chunk of slack)
        u64 dw2 = 0, X2 = 0; float4 vb2 = make_float4(0.f, 0.f, 0.f, 0.f);
        u64 gpn = 0;
        if (c + 2 < WORDS) {
            int nb2 = base + 128;
            dw2 = Mb[(size_t)(c + 2) * ROWS + nb2 + l];
            vb2 = bx[nb2 + l];
            if (c + 3 < WORDS) X2 = Mb[(size_t)(c + 3) * ROWS + nb2 + l];
            int K = kept;
            if (K > 0) {
                #pragma unroll
                for (int u = 0; u < 16; u++) {        // 16 indep loads/lane, clamp-dup (OR-idem)
                    int k = l + (u << 6);
                    u32 idx = keptIdx[(k < K) ? k : K - 1];
                    gpn |= Mb[(size_t)(c + 2) * ROWS + idx];
                }
            }
        }
        dw0 = dw1; X0 = X1; vb0 = vb1;
        dw1 = dw2; X1 = X2; vb1 = vb2;
        gp = gpn;
    }
    // tail stays zero from the d_out memset (matches valids==False -> zeros)
}

// ---------------- host ----------------
extern "C" void kernel_launch(void* const* d_in, const int* in_sizes, int n_in,
                              void* d_out, int out_size, void* d_ws, size_t ws_size,
                              hipStream_t stream) {
    const float* cls     = (const float*)d_in[0];   // rpn_class  (B,N,2)
    const float* bbox    = (const float*)d_in[1];   // rpn_bbox   (B,N,4)
    const float* anchors = (const float*)d_in[2];   // anchors    (B,N,4)

    char* ws = (char*)d_ws;
    u32* hist1 = (u32*)(ws);                        // 131072
    u32* meta  = (u32*)(ws + 131072);               // 256 B
    float4* boxes = (float4*)(ws + 131328);         // 8*6016*16 = 770048 -> end 901376
    float* areas  = (float*)(ws + 901376);          // 8*6016*4  = 192512 -> end 1093888
    u64* Mt = (u64*)(ws + 1093888);                 // 8*94*6016*8 = 36190208 -> end 37284096
    u64* cand = Mt;                                 // overlay: cand dead before Mt written
    size_t need = 1093888 + (size_t)NBATCH * WORDS * ROWS * 8;

    hipMemsetAsync(d_out, 0, (size_t)out_size * 4, stream);
    if (ws_size < need) return;
    hipMemsetAsync(ws, 0, 131328, stream);          // hist + meta

    hist_kernel<<<dim3(64, NBATCH), 256, 0, stream>>>(cls, hist1);
    scan_kernel<<<NBATCH, 256, 0, stream>>>(hist1, meta);
    compact_kernel<<<dim3(64, NBATCH), 256, 0, stream>>>(cls, meta, cand);
    rank_kernel<<<dim3(CAP / 256, NBATCH), 256, 0, stream>>>(cand, meta, anchors, bbox, boxes, areas);
    nms_mask_kernel<<<dim3(WORDS, (WORDS + 3) / 4, NBATCH), 256, 0, stream>>>(boxes, areas, Mt);
    nms_seq_kernel<<<NBATCH, 64, 0, stream>>>(boxes, Mt, (float*)d_out);
}

// Round 7
// 397.664 us; speedup vs baseline: 2.1428x; 1.0051x over previous
//
#include <hip/hip_runtime.h>
#include <cstdint>
#include <math.h>

#define NBATCH 8
#define NANCH 262144
#define TOPK 6000
#define OUTK 1000
#define CAP 16384
#define ROWS 6016          // TOPK padded to 94*64
#define WORDS 94           // ceil(6000/64)

using u32 = uint32_t;
using u64 = unsigned long long;

// ---------------- coarse top-k threshold: one 12-bit histogram pass ----------------
__global__ void hist_kernel(const float* __restrict__ cls, u32* __restrict__ hist) {
    __shared__ u32 lh[4096];
    int b = blockIdx.y, t = threadIdx.x;
    for (int i = t; i < 4096; i += 256) lh[i] = 0;
    __syncthreads();
    const float4* p4 = (const float4*)(cls + (size_t)b * NANCH * 2);
    const int P = NANCH / 2;
    for (int p = blockIdx.x * 256 + t; p < P; p += gridDim.x * 256) {
        float4 v = p4[p];
        atomicAdd(&lh[__float_as_uint(v.y) >> 20], 1);
        atomicAdd(&lh[__float_as_uint(v.w) >> 20], 1);
    }
    __syncthreads();
    for (int i = t; i < 4096; i += 256) { u32 c = lh[i]; if (c) atomicAdd(&hist[b * 4096 + i], c); }
}

// ---------------- compact: inline threshold scan + LDS staging, 1 atomic/block ----------
__global__ void compact_kernel(const float* __restrict__ cls, const u32* __restrict__ hist,
                               u32* __restrict__ meta, u64* __restrict__ cand) {
    __shared__ u64 buf[4096];
    __shared__ u32 ts[256];
    __shared__ u32 thr, lc, gbase;
    int b = blockIdx.y, t = threadIdx.x;
    if (t == 0) lc = 0;
    // every block recomputes the (deterministic) threshold from the histogram
    const u32* h = hist + b * 4096;
    u32 s = 0;
    for (int k = 0; k < 16; k++) s += h[t * 16 + k];
    ts[t] = s; __syncthreads();
    u32 suf = 0;
    for (int t2 = t + 1; t2 < 256; t2++) suf += ts[t2];
    if (suf < TOPK && suf + s >= TOPK) {
        u32 a = suf;
        for (int k = 15; k >= 0; k--) {
            u32 c = h[t * 16 + k];
            if (a + c >= TOPK) { thr = (u32)(t * 16 + k) << 20; break; }
            a += c;
        }
    }
    __syncthreads();
    u32 T = thr;
    const float4* p4 = (const float4*)(cls + (size_t)b * NANCH * 2);
    const int P = NANCH / 2;
    for (int p = blockIdx.x * 256 + t; p < P; p += gridDim.x * 256) {
        float4 v = p4[p];
        u32 k0 = __float_as_uint(v.y), k1 = __float_as_uint(v.w);
        u32 n0 = 2u * (u32)p, n1 = n0 + 1u;
        if (k0 >= T) { u32 q = atomicAdd(&lc, 1u); buf[q] = ((u64)k0 << 32) | (u32)(~n0); }
        if (k1 >= T) { u32 q = atomicAdd(&lc, 1u); buf[q] = ((u64)k1 << 32) | (u32)(~n1); }
    }
    __syncthreads();
    if (t == 0) gbase = atomicAdd(&meta[48 + b], lc);
    __syncthreads();
    u32 base = gbase, n = lc;
    for (u32 j = t; j < n; j += 256) {
        u32 d = base + j;
        if (d < CAP) cand[(size_t)b * CAP + d] = buf[j];
    }
}

// ---------------- cross-lane helpers ----------------
__device__ inline u64 shfl64(u64 x, int src) {
    int lo = __shfl((int)(u32)(x & 0xffffffffull), src, 64);
    int hi = __shfl((int)(u32)(x >> 32), src, 64);
    return ((u64)(u32)hi << 32) | (u32)lo;
}
__device__ inline u64 readlane64(u64 x, int sl) {
    u32 lo = (u32)__builtin_amdgcn_readlane((int)(u32)x, sl);
    u32 hi = (u32)__builtin_amdgcn_readlane((int)(u32)(x >> 32), sl);
    return ((u64)hi << 32) | lo;
}
__device__ inline u64 wave_or64(u64 x) {
    u32 lo = (u32)x, hi = (u32)(x >> 32);
    lo |= __builtin_amdgcn_ds_swizzle(lo, 0x041F); hi |= __builtin_amdgcn_ds_swizzle(hi, 0x041F);
    lo |= __builtin_amdgcn_ds_swizzle(lo, 0x081F); hi |= __builtin_amdgcn_ds_swizzle(hi, 0x081F);
    lo |= __builtin_amdgcn_ds_swizzle(lo, 0x101F); hi |= __builtin_amdgcn_ds_swizzle(hi, 0x101F);
    lo |= __builtin_amdgcn_ds_swizzle(lo, 0x201F); hi |= __builtin_amdgcn_ds_swizzle(hi, 0x201F);
    lo |= __builtin_amdgcn_ds_swizzle(lo, 0x401F); hi |= __builtin_amdgcn_ds_swizzle(hi, 0x401F);
    u32 l0 = (u32)__builtin_amdgcn_readlane((int)lo, 0)  | (u32)__builtin_amdgcn_readlane((int)lo, 32);
    u32 h0 = (u32)__builtin_amdgcn_readlane((int)hi, 0)  | (u32)__builtin_amdgcn_readlane((int)hi, 32);
    return ((u64)h0 << 32) | l0;
}

// ---------------- exact stable rank via 64-lane ring rotation; writes boxes+areas -------
__global__ void rank_kernel(const u64* __restrict__ cand, const u32* __restrict__ meta,
                            const float* __restrict__ anchors, const float* __restrict__ bbox,
                            float4* __restrict__ boxes, float* __restrict__ areas) {
    __shared__ u64 tile[2048];
    int b = blockIdx.y, t = threadIdx.x, l = t & 63;
    int c0 = blockIdx.x * 256 + t;
    u32 cnt = meta[48 + b]; if (cnt > CAP) cnt = CAP;
    if (blockIdx.x == 0 && t < ROWS - TOPK) {   // zero-pad rows 6000..6015
        boxes[(size_t)b * ROWS + TOPK + t] = make_float4(0.f, 0.f, 0.f, 0.f);
        areas[(size_t)b * ROWS + TOPK + t] = 0.f;
    }
    if (blockIdx.x * 256 >= (int)cnt) return;
    const u64* cb = cand + (size_t)b * CAP;
    u64 Kc = (c0 < (int)cnt) ? cb[c0] : 0ull;
    u32 rank = 0;
    for (u32 t0 = 0; t0 < cnt; t0 += 2048) {
        for (int q = t; q < 2048; q += 256)
            tile[q] = (t0 + (u32)q < cnt) ? cb[t0 + q] : 0ull;
        __syncthreads();
        u64 r[32];
        #pragma unroll
        for (int u = 0; u < 32; u++) r[u] = tile[l + (u << 6)];
        u64 kk = Kc; u32 cc = 0;
        for (int s = 0; s < 64; s++) {
            #pragma unroll
            for (int u = 0; u < 32; u++) cc += (r[u] > kk) ? 1u : 0u;
            int src = (l + 1) & 63;
            kk = shfl64(kk, src);
            cc = (u32)__shfl((int)cc, src, 64);
        }
        rank += cc;
        __syncthreads();
    }
    if (c0 < (int)cnt && rank < TOPK) {
        u32 idx = ~(u32)(Kc & 0xFFFFFFFFull);
        size_t off = ((size_t)b * NANCH + idx) * 4;
        const float4 a = *(const float4*)(anchors + off);
        const float4 d = *(const float4*)(bbox + off);
        float h = a.z - a.x, w = a.w - a.y;
        float cy = a.x + 0.5f * h, cx = a.y + 0.5f * w;
        float dy = d.x * 0.1f, dx = d.y * 0.1f, dh = d.z * 0.2f, dw = d.w * 0.2f;
        cy = cy + dy * h; cx = cx + dx * w;
        h = h * (float)exp((double)dh);
        w = w * (float)exp((double)dw);
        float y1 = cy - 0.5f * h, x1 = cx - 0.5f * w;
        float y2 = cy + 0.5f * h, x2 = cx + 0.5f * w;
        y1 = fminf(fmaxf(y1, 0.f), 1.f); x1 = fminf(fmaxf(x1, 0.f), 1.f);
        y2 = fminf(fmaxf(y2, 0.f), 1.f); x2 = fminf(fmaxf(x2, 0.f), 1.f);
        boxes[(size_t)b * ROWS + rank] = make_float4(y1, x1, y2, x2);
        areas[(size_t)b * ROWS + rank] = (y2 - y1) * (x2 - x1);  // same rounding as reference
    }
}

// ---------------- NMS phase A: lane=row, cols scalar-batched, branch-free ----------------
// Exact decision: RN(inter/uni) > 0.7f  <=>  inter >= MID*uni (reals), MID = 0.7f + 2^-25.
// Fast f32 path: d = fma(uni,-0.7f,inter); |d| > 2^-18*uni => sign decides. Waves with any
// borderline col (rare) redo the whole tile with an exact-sign f64 fma.
__global__ __launch_bounds__(256) void nms_mask_kernel(const float4* __restrict__ boxes,
                                                       const float* __restrict__ areas,
                                                       u64* __restrict__ Mt) {
    const float  EPS  = 3.8146972656e-06f;                       // 2^-18
    const double MIDD = (double)0.7f + 2.9802322387695312e-08;   // midpoint to nextup(0.7f)
    int cb = blockIdx.x, b = blockIdx.z;
    int wave = threadIdx.x >> 6, l = threadIdx.x & 63;
    int rt = blockIdx.y * 4 + wave;
    if (rt >= WORDS || cb < rt) return;          // strictly-below-diagonal words never read
    const float4* bx = boxes + (size_t)b * ROWS;
    const float*  ar = areas + (size_t)b * ROWS;
    int row = rt * 64 + l;
    float4 r4 = bx[row];                         // lane l = row rt*64+l (vector load)
    float  rar = ar[row];
    const float4* cbp = bx + cb * 64;            // cols: uniform-indexed -> scalar loads
    const float*  cap = ar + cb * 64;
    u32 wlo = 0, whi = 0; u64 unc = 0;
    #pragma unroll
    for (int blk = 7; blk >= 0; blk--) {         // cols 63..0, shift-or accumulation
        float4 c8[8]; float a8[8];
        #pragma unroll
        for (int i = 0; i < 8; i++) { c8[i] = cbp[blk * 8 + i]; a8[i] = cap[blk * 8 + i]; }
        #pragma unroll
        for (int i = 7; i >= 0; i--) {
            int c = blk * 8 + i;
            float y1 = fmaxf(r4.x, c8[i].x), x1 = fmaxf(r4.y, c8[i].y);
            float y2 = fminf(r4.z, c8[i].z), x2 = fminf(r4.w, c8[i].w);
            float inter = fmaxf(y2 - y1, 0.f) * fmaxf(x2 - x1, 0.f);
            float uni = ((rar + a8[i]) - inter) + 1e-9f;   // assoc matches reference
            float d = fmaf(uni, -0.7f, inter);
            float tt = uni * EPS;
            u32 sup = (d > tt) ? 1u : 0u;
            unc |= __ballot(fabsf(d) <= tt);
            if (c >= 32) whi = (whi << 1) | sup;
            else         wlo = (wlo << 1) | sup;
        }
    }
    if (unc) {                                   // wave-uniform, rare (~3% of tiles)
        wlo = 0; whi = 0;
        for (int c = 63; c >= 0; c--) {
            float4 cc4 = cbp[c]; float caf = cap[c];
            float y1 = fmaxf(r4.x, cc4.x), x1 = fmaxf(r4.y, cc4.y);
            float y2 = fminf(r4.z, cc4.z), x2 = fminf(r4.w, cc4.w);
            float inter = fmaxf(y2 - y1, 0.f) * fmaxf(x2 - x1, 0.f);
            float uni = ((rar + caf) - inter) + 1e-9f;
            double td = fma((double)uni, -MIDD, (double)inter);
            u32 sup = (td >= 0.0) ? 1u : 0u;     // exact sign; tie -> suppress (RN ties up)
            if (c >= 32) whi = (whi << 1) | sup;
            else         wlo = (wlo << 1) | sup;
        }
    }
    u64 w = ((u64)whi << 32) | wlo;
    if (cb == rt) w &= (l < 63) ? (~0ull << (l + 1)) : 0ull;   // cols > row only
    Mt[((size_t)b * WORDS + cb) * ROWS + row] = w;             // coalesced full-line store
}

// ---------------- NMS phase B: scalar-unit greedy, swizzle reduce, 2-deep prefetch -------
__global__ __launch_bounds__(64) void nms_seq_kernel(const float4* __restrict__ boxes,
                                                     const u64* __restrict__ Mt,
                                                     float* __restrict__ out) {
    __shared__ u32 keptIdx[1024];
    int b = blockIdx.x, l = threadIdx.x;
    const u64* Mb = Mt + (size_t)b * WORDS * ROWS;    // Mb[word*ROWS + row]
    const float4* bx = boxes + (size_t)b * ROWS;
    float4* ob = (float4*)(out + (size_t)b * OUTK * 4);
    int kept = 0;
    u64 rw = 0;
    u64 dw0 = Mb[l];                                  // diag word of chunk 0
    float4 vb0 = bx[l];
    u64 X0 = Mb[(size_t)ROWS + l];                    // chunk-0 rows -> word 1
    u64 dw1 = Mb[(size_t)ROWS + 64 + l];              // diag word of chunk 1
    float4 vb1 = bx[64 + l];
    u64 X1 = Mb[(size_t)2 * ROWS + 64 + l];           // chunk-1 rows -> word 2
    u64 gp = 0;
    for (int c = 0; c < WORDS; c++) {
        int base = c * 64;
        u64 valid = (base + 64 <= TOPK) ? ~0ull : ((1ull << (TOPK - base)) - 1);
        u64 alive = ~rw & valid;
        u64 km = 0, xk = 0; int kt = kept;
        while (alive && kt < OUTK) {                  // greedy: SALU/readlane only
            int j = __builtin_amdgcn_readfirstlane((int)__builtin_ctzll(alive));
            km |= 1ull << j; kt++;
            u64 dwj = readlane64(dw0, j);
            xk |= readlane64(X0, j);
            alive &= ~dwj & ~(1ull << j);
        }
        if ((km >> l) & 1) {
            int pos = kept + __popcll(km & ((1ull << l) - 1));
            ob[pos] = vb0;
            keptIdx[pos] = (u32)(base + l);
        }
        kept = kt;
        if (kept >= OUTK || c + 1 >= WORDS) break;
        rw = xk | wave_or64(gp);
        __syncthreads();
        u64 dw2 = 0, X2 = 0; float4 vb2 = make_float4(0.f, 0.f, 0.f, 0.f);
        u64 gpn = 0;
        if (c + 2 < WORDS) {
            int nb2 = base + 128;
            dw2 = Mb[(size_t)(c + 2) * ROWS + nb2 + l];
            vb2 = bx[nb2 + l];
            if (c + 3 < WORDS) X2 = Mb[(size_t)(c + 3) * ROWS + nb2 + l];
            int K = kept;
            if (K > 0) {
                #pragma unroll
                for (int u = 0; u < 16; u++) {
                    int k = l + (u << 6);
                    u32 idx = keptIdx[(k < K) ? k : K - 1];
                    gpn |= Mb[(size_t)(c + 2) * ROWS + idx];
                }
            }
        }
        dw0 = dw1; X0 = X1; vb0 = vb1;
        dw1 = dw2; X1 = X2; vb1 = vb2;
        gp = gpn;
    }
    // tail zeros (replaces d_out memset): positions [kept, OUTK)
    for (int p = kept + l; p < OUTK; p += 64)
        ob[p] = make_float4(0.f, 0.f, 0.f, 0.f);
}

// ---------------- host ----------------
extern "C" void kernel_launch(void* const* d_in, const int* in_sizes, int n_in,
                              void* d_out, int out_size, void* d_ws, size_t ws_size,
                              hipStream_t stream) {
    const float* cls     = (const float*)d_in[0];   // rpn_class  (B,N,2)
    const float* bbox    = (const float*)d_in[1];   // rpn_bbox   (B,N,4)
    const float* anchors = (const float*)d_in[2];   // anchors    (B,N,4)

    char* ws = (char*)d_ws;
    u32* hist1 = (u32*)(ws);                        // 131072
    u32* meta  = (u32*)(ws + 131072);               // 256 B (count @48+b)
    float4* boxes = (float4*)(ws + 131328);         // 8*6016*16 = 770048 -> end 901376
    float* areas  = (float*)(ws + 901376);          // 8*6016*4  = 192512 -> end 1093888
    u64* Mt = (u64*)(ws + 1093888);                 // 8*94*6016*8 = 36190208 -> end 37284096
    u64* cand = Mt;                                 // overlay: cand dead before Mt written
    size_t need = 1093888 + (size_t)NBATCH * WORDS * ROWS * 8;
    if (ws_size < need) return;

    hipMemsetAsync(ws, 0, 131328, stream);          // hist + meta

    hist_kernel<<<dim3(64, NBATCH), 256, 0, stream>>>(cls, hist1);
    compact_kernel<<<dim3(64, NBATCH), 256, 0, stream>>>(cls, hist1, meta, cand);
    rank_kernel<<<dim3(CAP / 256, NBATCH), 256, 0, stream>>>(cand, meta, anchors, bbox, boxes, areas);
    nms_mask_kernel<<<dim3(WORDS, (WORDS + 3) / 4, NBATCH), 256, 0, stream>>>(boxes, areas, Mt);
    nms_seq_kernel<<<NBATCH, 64, 0, stream>>>(boxes, Mt, (float*)d_out);
}